// Round 10
// baseline (354.141 us; speedup 1.0000x reference)
//
#include <hip/hip_runtime.h>

// GCN: out[m,n,o] = (A_hat relu(A_hat (x W1) + b1) W_out[m])[n,o] + b_out[m,o]
// A_hat = D^-1/2 (A + I) D^-1/2.
// R10 = R9 with prop1s restructured: XCD-resident 16-col slices (proven: FETCH
// 150->33MB) AND uint4 16B loads (proven: R6 instruction density).
//  - wave = 32 edge-groups x 2 lanes; per 32 edges/slice: 1 shfl + 1 uint4 load.
//  - per-node: 5-step even-offset shfl_xor reduction (il-preserving), self-loop
//    added ONCE after reduction, relu, 8-way projection via shfl(y, 0/1).

constexpr int CIN = 128;
constexpr int SSHIFT = 8;        // 256 nodes per super-bucket
constexpr int NBLKB = 256;       // partition blocks == scan chunk size
constexpr int CSR_CAP = 10240;   // LDS sort capacity (mean ~8163, std ~90)

typedef __attribute__((ext_vector_type(8))) short short8v;
typedef __attribute__((ext_vector_type(4))) float float4v;

__device__ inline unsigned pack_bf16x2(float a, float b) {
  unsigned ua = __float_as_uint(a), ub = __float_as_uint(b);
  ua = (ua + 0x7FFFu + ((ua >> 16) & 1u)) >> 16;
  ub = (ub + 0x7FFFu + ((ub >> 16) & 1u)) >> 16;
  return ua | (ub << 16);
}
__device__ inline float bf_lo(unsigned u) { return __uint_as_float(u << 16); }
__device__ inline float bf_hi(unsigned u) { return __uint_as_float(u & 0xFFFF0000u); }

// ---------- pass A: per-block super-bucket histogram ----------
__global__ __launch_bounds__(256) void histsb_k(const int* __restrict__ dst,
    int* __restrict__ blockhist, int E, int nsb) {
  __shared__ int lh[256];
  int b = blockIdx.x, t = threadIdx.x;
  lh[t] = 0;
  __syncthreads();
  int per = (E + gridDim.x - 1) / gridDim.x;
  int s0 = b * per, s1 = min(E, s0 + per);
  for (int i = s0 + t; i < s1; i += 256) atomicAdd(&lh[dst[i] >> SSHIFT], 1);
  __syncthreads();
  if (t < nsb) blockhist[t * NBLKB + b] = lh[t];
}

// exclusive scan, chunk = blockDim entries; btot==nullptr for top level
__global__ void scan_k(const int* __restrict__ v_in,
    int* __restrict__ excl_out, int* __restrict__ btot, int n) {
  __shared__ int wsum[16];
  int t = threadIdx.x, l = t & 63, w = t >> 6;
  int nw = blockDim.x >> 6;
  int i = blockIdx.x * blockDim.x + t;
  int v = (i < n) ? v_in[i] : 0;
  int orig = v;
  #pragma unroll
  for (int off = 1; off < 64; off <<= 1) {
    int u = __shfl_up(v, off);
    if (l >= off) v += u;
  }
  if (l == 63) wsum[w] = v;
  __syncthreads();
  int add = 0;
  for (int j = 0; j < nw; ++j) if (j < w) add += wsum[j];
  v += add;
  if (i < n) excl_out[i] = v - orig;
  if (t == (int)blockDim.x - 1 && btot != nullptr) btot[blockIdx.x] = v;
}

// ---------- pass B: write edges to exact (block,super) ranges ----------
__global__ __launch_bounds__(256) void stageB_k(const int* __restrict__ src,
    const int* __restrict__ dst, const int* __restrict__ soff,
    const int* __restrict__ boff, unsigned* __restrict__ stage, int E, int nsb) {
  __shared__ int loff[256];
  int b = blockIdx.x, t = threadIdx.x;
  if (t < nsb) loff[t] = soff[t * NBLKB + b] + boff[t];
  __syncthreads();
  int per = (E + gridDim.x - 1) / gridDim.x;
  int s0 = b * per, s1 = min(E, s0 + per);
  for (int i = s0 + t; i < s1; i += 256) {
    int d = dst[i], s = src[i];
    int pos = atomicAdd(&loff[d >> SSHIFT], 1);
    stage[pos] = (unsigned)s | ((unsigned)(d & 255) << 17);  // src<2^17, dloc 8b
  }
}

// ---------- per-super LDS count-sort: stage -> per-node CSR + dinv ----------
__global__ __launch_bounds__(256) void csrsb_k(const unsigned* __restrict__ stage,
    const int* __restrict__ boff, int* __restrict__ row_ptr, int* __restrict__ csr,
    float* __restrict__ dinv, int N, int E, int nsb) {
  __shared__ int cnt[256], off[256], cur[256];
  __shared__ unsigned ebuf[CSR_CAP];
  __shared__ int sbuf[CSR_CAP];
  __shared__ int wsum[4];
  int k = blockIdx.x, t = threadIdx.x, l = t & 63, w = t >> 6;
  cnt[t] = 0; cur[t] = 0;
  __syncthreads();
  int r0 = boff[k];
  int r1 = (k + 1 < nsb) ? boff[k + 1] : E;
  int len = r1 - r0;
  bool fits = len <= CSR_CAP;
  if (fits) {
    for (int i = t; i < len; i += 256) {
      unsigned s = stage[r0 + i];
      ebuf[i] = s;
      atomicAdd(&cnt[s >> 17], 1);
    }
  } else {
    for (int i = r0 + t; i < r1; i += 256) atomicAdd(&cnt[stage[i] >> 17], 1);
  }
  __syncthreads();
  {  // 256-entry exclusive scan (4 waves)
    int v = cnt[t], orig = v;
    #pragma unroll
    for (int o = 1; o < 64; o <<= 1) {
      int u = __shfl_up(v, o);
      if (l >= o) v += u;
    }
    if (l == 63) wsum[w] = v;
    __syncthreads();
    int add = 0;
    #pragma unroll
    for (int j = 0; j < 4; ++j) if (j < w) add += wsum[j];
    int excl = v + add - orig;
    off[t] = excl;
    int n = (k << SSHIFT) + t;
    if (n < N) {
      row_ptr[n] = r0 + excl;
      dinv[n] = rsqrtf((float)(orig + 1));
    }
    if (k == nsb - 1 && t == 255) row_ptr[N] = E;
  }
  __syncthreads();
  if (fits) {
    for (int i = t; i < len; i += 256) {
      unsigned s = ebuf[i];
      int dl = s >> 17;
      int pos = off[dl] + atomicAdd(&cur[dl], 1);
      sbuf[pos] = (int)(s & 0x1FFFF);
    }
    __syncthreads();
    for (int i = t; i < len; i += 256) csr[r0 + i] = sbuf[i];
  } else {
    for (int i = r0 + t; i < r1; i += 256) {
      unsigned s = stage[i];
      int dl = s >> 17;
      int pos = r0 + off[dl] + atomicAdd(&cur[dl], 1);
      csr[pos] = (int)(s & 0x1FFFF);
    }
  }
}

// ---------- g(bf16, slice-major) = dinv[n]*(x@W1) via MFMA split-bf16 ----------
__device__ inline void split8(const float* f, short8v& ah, short8v& al) {
  #pragma unroll
  for (int j = 0; j < 8; ++j) {
    unsigned ua = __float_as_uint(f[j]);
    unsigned hb = (ua + 0x7FFFu + ((ua >> 16) & 1u)) >> 16;
    float fh = __uint_as_float(hb << 16);
    float rl = f[j] - fh;
    unsigned ub = __float_as_uint(rl);
    unsigned lb = (ub + 0x7FFFu + ((ub >> 16) & 1u)) >> 16;
    ah[j] = (short)hb;
    al[j] = (short)lb;
  }
}

__global__ __launch_bounds__(256) void gemm_k(const float* __restrict__ x,
    const float* __restrict__ W, const float* __restrict__ dinv,
    unsigned* __restrict__ gu, int nrows) {
  __shared__ unsigned short Bh[16384];  // [kstep][coltile][lane][j] bf16 bits
  __shared__ unsigned short Bl[16384];
  int t = threadIdx.x, l = t & 63, w = t >> 6;
  for (int idx = t; idx < 16384; idx += 256) {
    int k = idx >> 7, col = idx & 127;
    float wv = W[idx];
    unsigned ua = __float_as_uint(wv);
    unsigned hb = (ua + 0x7FFFu + ((ua >> 16) & 1u)) >> 16;
    float fh = __uint_as_float(hb << 16);
    float rl = wv - fh;
    unsigned ub = __float_as_uint(rl);
    unsigned lb = (ub + 0x7FFFu + ((ub >> 16) & 1u)) >> 16;
    int addr = (((k >> 5) * 8 + (col >> 4)) * 64 +
                (((k >> 3) & 3) * 16 + (col & 15))) * 8 + (k & 7);
    Bh[addr] = (unsigned short)hb;
    Bl[addr] = (unsigned short)lb;
  }
  __syncthreads();

  int row0 = blockIdx.x * 128;
  int ct0 = w * 2;
  float4v acc[8][2];
  #pragma unroll
  for (int i = 0; i < 8; ++i) { acc[i][0] = (float4v)0.f; acc[i][1] = (float4v)0.f; }
  int arow = row0 + (l & 15);
  int kln = (l >> 4) * 8;

  for (int ks = 0; ks < 4; ++ks) {
    short8v bh0 = *(short8v*)&Bh[((ks * 8 + ct0) * 64 + l) * 8];
    short8v bh1 = *(short8v*)&Bh[((ks * 8 + ct0 + 1) * 64 + l) * 8];
    short8v bl0 = *(short8v*)&Bl[((ks * 8 + ct0) * 64 + l) * 8];
    short8v bl1 = *(short8v*)&Bl[((ks * 8 + ct0 + 1) * 64 + l) * 8];
    #pragma unroll
    for (int rt = 0; rt < 8; ++rt) {
      int r = arow + rt * 16;
      const float* xp = &x[(size_t)min(r, nrows - 1) * CIN + ks * 32 + kln];
      float f[8];
      *(float4*)&f[0] = *(const float4*)xp;
      *(float4*)&f[4] = *(const float4*)(xp + 4);
      short8v ah, al;
      split8(f, ah, al);
      acc[rt][0] = __builtin_amdgcn_mfma_f32_16x16x32_bf16(ah, bh0, acc[rt][0], 0, 0, 0);
      acc[rt][1] = __builtin_amdgcn_mfma_f32_16x16x32_bf16(ah, bh1, acc[rt][1], 0, 0, 0);
      acc[rt][0] = __builtin_amdgcn_mfma_f32_16x16x32_bf16(ah, bl0, acc[rt][0], 0, 0, 0);
      acc[rt][1] = __builtin_amdgcn_mfma_f32_16x16x32_bf16(ah, bl1, acc[rt][1], 0, 0, 0);
      acc[rt][0] = __builtin_amdgcn_mfma_f32_16x16x32_bf16(al, bh0, acc[rt][0], 0, 0, 0);
      acc[rt][1] = __builtin_amdgcn_mfma_f32_16x16x32_bf16(al, bh1, acc[rt][1], 0, 0, 0);
    }
  }
  // D col = l&15, row = 4*(l>>4)+reg [HW-verified]; slice = coltile (16 cols)
  #pragma unroll
  for (int rt = 0; rt < 8; ++rt) {
    #pragma unroll
    for (int r = 0; r < 4; ++r) {
      int row = row0 + rt * 16 + (l >> 4) * 4 + r;
      bool ok = row < nrows;
      float dv = ok ? dinv[row] : 0.f;
      #pragma unroll
      for (int c = 0; c < 2; ++c) {
        float val = acc[rt][c][r] * dv;
        float other = __shfl_xor(val, 1);
        int slice = ct0 + c;
        if (ok && !(l & 1))
          gu[((size_t)slice * nrows + row) * 8 + ((l & 15) >> 1)] = pack_bf16x2(val, other);
      }
    }
  }
}

// ---------- propagate-1: XCD-sliced uint4 gather + fused projection ----------
#define ACC8(U) do { \
  acc[0] += bf_lo((U).x); acc[1] += bf_hi((U).x); \
  acc[2] += bf_lo((U).y); acc[3] += bf_hi((U).y); \
  acc[4] += bf_lo((U).z); acc[5] += bf_hi((U).z); \
  acc[6] += bf_lo((U).w); acc[7] += bf_hi((U).w); } while (0)

__global__ __launch_bounds__(256) void prop1s_k(const uint4* __restrict__ gs4,
    const int* __restrict__ row_ptr, const int* __restrict__ csr,
    const float* __restrict__ dinv, const float* __restrict__ b1,
    const float* __restrict__ Wout, float* __restrict__ g2part,
    int N, int waves_per_slice) {
  int slice = blockIdx.x & 7;          // XCD round-robin; slice = 1.6MB, L2-resident
  int chunk = blockIdx.x >> 3;
  int t = threadIdx.x, l = t & 63, w = t >> 6;
  int gi = l >> 1, il = l & 1;         // 32 edge-groups x 2 lanes (16B each)
  // lane's 8 cols: global cols slice*16 + il*8 + c
  float bb[8];
  #pragma unroll
  for (int c = 0; c < 8; ++c) bb[c] = b1[slice * 16 + il * 8 + c];
  // projection weights for this lane's output j = l&7 over all 16 slice cols
  int j = l & 7;
  float wl[8], wh[8];
  #pragma unroll
  for (int c = 0; c < 8; ++c) {
    wl[c] = Wout[(j >> 1) * 256 + (slice * 16 + c) * 2 + (j & 1)];
    wh[c] = Wout[(j >> 1) * 256 + (slice * 16 + 8 + c) * 2 + (j & 1)];
  }
  const uint4* gb4 = gs4 + (size_t)slice * N * 2 + il;
  float* gp = g2part + (size_t)slice * N * 8;

  int wsl = chunk * 4 + w;
  for (int n = wsl; n < N; n += waves_per_slice) {
    int start = row_ptr[n], end = row_ptr[n + 1];
    float d = dinv[n];
    float acc[8];
    #pragma unroll
    for (int c = 0; c < 8; ++c) acc[c] = 0.f;
    for (int base = start; base < end; base += 64) {
      int cnt = min(64, end - base);
      int eb = (base + l < end) ? csr[base + l] : 0;
      int i = 0;
      for (; i + 32 <= cnt; i += 32) {
        int sa = __shfl(eb, i + gi);
        uint4 u = gb4[(size_t)sa * 2];
        ACC8(u);
      }
      if (i < cnt) {
        int idx = i + gi;
        int sa = __shfl(eb, idx < cnt ? idx : i);
        if (idx < cnt) {
          uint4 u = gb4[(size_t)sa * 2];
          ACC8(u);
        }
      }
    }
    // reduce over the 32 edge-groups (even offsets preserve il)
    #pragma unroll
    for (int c = 0; c < 8; ++c) {
      acc[c] += __shfl_xor(acc[c], 2);
      acc[c] += __shfl_xor(acc[c], 4);
      acc[c] += __shfl_xor(acc[c], 8);
      acc[c] += __shfl_xor(acc[c], 16);
      acc[c] += __shfl_xor(acc[c], 32);
    }
    // self-loop exactly once (uniform across gi)
    uint4 us = gb4[(size_t)n * 2];
    ACC8(us);
    // relu on owning lanes (values uniform within il class)
    float y[8];
    #pragma unroll
    for (int c = 0; c < 8; ++c) y[c] = fmaxf(fmaf(acc[c], d, bb[c]), 0.f);
    // projection: pull y from lane 0 (il=0, cols 0-7) and lane 1 (il=1, cols 8-15)
    float p = 0.f;
    #pragma unroll
    for (int c = 0; c < 8; ++c) {
      float ylo = __shfl(y[c], 0);
      float yhi = __shfl(y[c], 1);
      p = fmaf(ylo, wl[c], p);
      p = fmaf(yhi, wh[c], p);
    }
    if (l < 8) gp[(size_t)n * 8 + l] = p;
  }
}

// ---------- finalize: sum slice partials, apply dinv, pack bf16 ----------
__global__ __launch_bounds__(256) void finalize_k(const float* __restrict__ g2part,
    const float* __restrict__ dinv, unsigned* __restrict__ g2w, int N) {
  int tid = blockIdx.x * 256 + threadIdx.x;
  if (tid >= N * 4) return;
  int n = tid >> 2, jp = tid & 3;
  float s0 = 0.f, s1 = 0.f;
  #pragma unroll
  for (int s = 0; s < 8; ++s) {
    const float* p = &g2part[((size_t)s * N + n) * 8 + jp * 2];
    s0 += p[0]; s1 += p[1];
  }
  float d = dinv[n];
  g2w[n * 4 + jp] = pack_bf16x2(d * s0, d * s1);
}

// ---------- propagate-2: 2 threads/node, uint2 bf16x4 per edge ----------
__global__ __launch_bounds__(256) void prop2_k(const uint2* __restrict__ g2v,
    const int* __restrict__ row_ptr, const int* __restrict__ csr,
    const float* __restrict__ dinv, const float* __restrict__ bout,
    float* __restrict__ out, int N) {
  int tid = blockIdx.x * 256 + threadIdx.x;
  int n = tid >> 1, hf = tid & 1;
  if (n >= N) return;
  uint2 us = g2v[n * 2 + hf];      // self-loop
  float a0 = bf_lo(us.x), a1 = bf_hi(us.x);
  float a2 = bf_lo(us.y), a3 = bf_hi(us.y);
  int e = row_ptr[n], e1 = row_ptr[n + 1];
  for (; e + 4 <= e1; e += 4) {
    int i0 = csr[e], i1 = csr[e + 1], i2 = csr[e + 2], i3 = csr[e + 3];
    uint2 u0 = g2v[i0 * 2 + hf], u1 = g2v[i1 * 2 + hf];
    uint2 u2 = g2v[i2 * 2 + hf], u3 = g2v[i3 * 2 + hf];
    a0 += (bf_lo(u0.x) + bf_lo(u1.x)) + (bf_lo(u2.x) + bf_lo(u3.x));
    a1 += (bf_hi(u0.x) + bf_hi(u1.x)) + (bf_hi(u2.x) + bf_hi(u3.x));
    a2 += (bf_lo(u0.y) + bf_lo(u1.y)) + (bf_lo(u2.y) + bf_lo(u3.y));
    a3 += (bf_hi(u0.y) + bf_hi(u1.y)) + (bf_hi(u2.y) + bf_hi(u3.y));
  }
  for (; e < e1; ++e) {
    uint2 u = g2v[csr[e] * 2 + hf];
    a0 += bf_lo(u.x); a1 += bf_hi(u.x);
    a2 += bf_lo(u.y); a3 += bf_hi(u.y);
  }
  float d = dinv[n];
  float2 o0 = make_float2(fmaf(d, a0, bout[hf * 4 + 0]), fmaf(d, a1, bout[hf * 4 + 1]));
  float2 o1 = make_float2(fmaf(d, a2, bout[hf * 4 + 2]), fmaf(d, a3, bout[hf * 4 + 3]));
  *(float2*)&out[(size_t)(hf * 2 + 0) * (2 * N) + 2 * n] = o0;
  *(float2*)&out[(size_t)(hf * 2 + 1) * (2 * N) + 2 * n] = o1;
}

extern "C" void kernel_launch(void* const* d_in, const int* in_sizes, int n_in,
                              void* d_out, int out_size, void* d_ws, size_t ws_size,
                              hipStream_t stream) {
  const float* x    = (const float*)d_in[0];
  const int*   ei   = (const int*)d_in[1];
  const float* W1   = (const float*)d_in[2];
  const float* b1   = (const float*)d_in[3];
  const float* Wout = (const float*)d_in[4];
  const float* bout = (const float*)d_in[5];
  float* out = (float*)d_out;

  const int N = in_sizes[0] / CIN;       // 50000
  const int E = in_sizes[1] / 2;         // 1600000
  const int* srcp = ei;
  const int* dstp = ei + E;
  const int NSB = (N + 255) >> SSHIFT;   // 196 super-buckets
  const int NSC = NSB * NBLKB;           // 50176 scan entries

  char* ws = (char*)d_ws;
  size_t off = 0;
  auto alloc = [&](size_t bytes) -> void* {
    void* p = ws + off;
    off = (off + bytes + 511) & ~(size_t)511;
    return p;
  };
  unsigned*       gu        = (unsigned*)alloc((size_t)N * 64 * 4);      // bf16 g, slice-major
  float*          g2part    = (float*)alloc((size_t)8 * N * 8 * 4);      // fp32 partials
  unsigned short* g2u       = (unsigned short*)alloc((size_t)N * 8 * 2); // bf16 g2
  float*          dinv      = (float*)alloc((size_t)N * 4);
  int*            blockhist = (int*)alloc((size_t)NSC * 4);
  int*            soff      = (int*)alloc((size_t)NSC * 4);
  int*            btot      = (int*)alloc(256 * 4);
  int*            boff      = (int*)alloc(256 * 4);
  int*            row_ptr   = (int*)alloc((size_t)(N + 1) * 4);
  int*            csr       = (int*)alloc((size_t)E * 4);
  unsigned*       stage     = (unsigned*)alloc((size_t)E * 4);
  (void)ws_size; (void)n_in; (void)out_size;

  histsb_k<<<NBLKB, 256, 0, stream>>>(dstp, blockhist, E, NSB);
  scan_k<<<NSB, 256, 0, stream>>>(blockhist, soff, btot, NSC);   // level 1
  scan_k<<<1, 256, 0, stream>>>(btot, boff, nullptr, NSB);       // level 2
  stageB_k<<<NBLKB, 256, 0, stream>>>(srcp, dstp, soff, boff, stage, E, NSB);
  csrsb_k<<<NSB, 256, 0, stream>>>(stage, boff, row_ptr, csr, dinv, N, E, NSB);

  gemm_k<<<(N + 127) / 128, 256, 0, stream>>>(x, W1, dinv, gu, N);

  const int P1_BLOCKS = 2048;            // 256 chunks x 8 slices
  prop1s_k<<<P1_BLOCKS, 256, 0, stream>>>((const uint4*)gu, row_ptr, csr, dinv, b1,
                                          Wout, g2part, N, (P1_BLOCKS / 8) * 4);
  finalize_k<<<(N * 4 + 255) / 256, 256, 0, stream>>>(g2part, dinv, (unsigned*)g2u, N);
  prop2_k<<<(2 * N + 255) / 256, 256, 0, stream>>>((const uint2*)g2u, row_ptr, csr,
                                                   dinv, bout, out, N);
}

// Round 11
// 135.837 us; speedup vs baseline: 2.6071x; 2.6071x over previous
//
#include <hip/hip_runtime.h>

// GCN: out[m,n,o] = (A_hat relu(A_hat (x W1) + b1) W_out[m])[n,o] + b_out[m,o]
// A_hat = D^-1/2 (A + I) D^-1/2.
// R11 = best-proven components + gemm split-staging fix + fewer launches:
//  - prep: super-bucket radix partition (R9), top-level scan recomputed
//    inline in stageB/csrsb (drops scan-L2 launch).
//  - gemm: MFMA split-bf16, x-tile split ONCE per k-step into LDS
//    (4x less split VALU than per-wave splitting); row-major bf16 g.
//  - prop1: R6 full-occupancy gather, 16 lanes x uint4/row, 4-deep ILP,
//    fused relu + 8-col projection (proven 55us).
//  - prop2: 2 threads/node, uint2 bf16x4 per edge (proven).

constexpr int CIN = 128;
constexpr int SSHIFT = 8;        // 256 nodes per super-bucket
constexpr int NBLKB = 256;       // partition blocks == scan chunk size
constexpr int CSR_CAP = 10240;   // LDS sort capacity (mean ~8163, std ~90)

typedef __attribute__((ext_vector_type(8))) short short8v;
typedef __attribute__((ext_vector_type(4))) float float4v;

__device__ inline unsigned pack_bf16x2(float a, float b) {
  unsigned ua = __float_as_uint(a), ub = __float_as_uint(b);
  ua = (ua + 0x7FFFu + ((ua >> 16) & 1u)) >> 16;
  ub = (ub + 0x7FFFu + ((ub >> 16) & 1u)) >> 16;
  return ua | (ub << 16);
}
__device__ inline float bf_lo(unsigned u) { return __uint_as_float(u << 16); }
__device__ inline float bf_hi(unsigned u) { return __uint_as_float(u & 0xFFFF0000u); }
__device__ inline void split1(float v, unsigned short& h, unsigned short& lo) {
  unsigned ua = __float_as_uint(v);
  unsigned hb = (ua + 0x7FFFu + ((ua >> 16) & 1u)) >> 16;
  float fh = __uint_as_float(hb << 16);
  float rl = v - fh;
  unsigned ub = __float_as_uint(rl);
  h = (unsigned short)hb;
  lo = (unsigned short)((ub + 0x7FFFu + ((ub >> 16) & 1u)) >> 16);
}

// ---------- pass A: per-block super-bucket histogram ----------
__global__ __launch_bounds__(256) void histsb_k(const int* __restrict__ dst,
    int* __restrict__ blockhist, int E, int nsb) {
  __shared__ int lh[256];
  int b = blockIdx.x, t = threadIdx.x;
  lh[t] = 0;
  __syncthreads();
  int per = (E + gridDim.x - 1) / gridDim.x;
  int s0 = b * per, s1 = min(E, s0 + per);
  for (int i = s0 + t; i < s1; i += 256) atomicAdd(&lh[dst[i] >> SSHIFT], 1);
  __syncthreads();
  if (t < nsb) blockhist[t * NBLKB + b] = lh[t];
}

// exclusive scan over NSC entries, 256/block; writes per-chunk totals
__global__ __launch_bounds__(256) void scan_k(const int* __restrict__ v_in,
    int* __restrict__ excl_out, int* __restrict__ btot, int n) {
  __shared__ int wsum[4];
  int t = threadIdx.x, l = t & 63, w = t >> 6;
  int i = blockIdx.x * 256 + t;
  int v = (i < n) ? v_in[i] : 0;
  int orig = v;
  #pragma unroll
  for (int off = 1; off < 64; off <<= 1) {
    int u = __shfl_up(v, off);
    if (l >= off) v += u;
  }
  if (l == 63) wsum[w] = v;
  __syncthreads();
  int add = 0;
  #pragma unroll
  for (int j = 0; j < 4; ++j) if (j < w) add += wsum[j];
  v += add;
  if (i < n) excl_out[i] = v - orig;
  if (t == 255) btot[blockIdx.x] = v;
}

// ---------- pass B: write edges to exact (block,super) ranges ----------
// top-level (196-entry) scan of btot recomputed inline per block.
__global__ __launch_bounds__(256) void stageB_k(const int* __restrict__ src,
    const int* __restrict__ dst, const int* __restrict__ soff,
    const int* __restrict__ btot, unsigned* __restrict__ stage, int E, int nsb) {
  __shared__ int loff[256];
  __shared__ int wsum[4];
  int b = blockIdx.x, t = threadIdx.x, l = t & 63, w = t >> 6;
  int bv = (t < nsb) ? btot[t] : 0;
  int vv = bv;
  #pragma unroll
  for (int o = 1; o < 64; o <<= 1) { int u = __shfl_up(vv, o); if (l >= o) vv += u; }
  if (l == 63) wsum[w] = vv;
  __syncthreads();
  int add = 0;
  #pragma unroll
  for (int j = 0; j < 4; ++j) if (j < w) add += wsum[j];
  int bexcl = vv + add - bv;           // exclusive prefix of btot at t
  if (t < nsb) loff[t] = soff[t * NBLKB + b] + bexcl;
  __syncthreads();
  int per = (E + gridDim.x - 1) / gridDim.x;
  int s0 = b * per, s1 = min(E, s0 + per);
  for (int i = s0 + t; i < s1; i += 256) {
    int d = dst[i], s = src[i];
    int pos = atomicAdd(&loff[d >> SSHIFT], 1);
    stage[pos] = (unsigned)s | ((unsigned)(d & 255) << 17);  // src<2^17, dloc 8b
  }
}

// ---------- per-super LDS count-sort: stage -> per-node CSR + dinv ----------
__global__ __launch_bounds__(256) void csrsb_k(const unsigned* __restrict__ stage,
    const int* __restrict__ btot, int* __restrict__ row_ptr, int* __restrict__ csr,
    float* __restrict__ dinv, int N, int E, int nsb) {
  __shared__ int cnt[256], off[256], cur[256], sboff[256];
  __shared__ unsigned ebuf[CSR_CAP];
  __shared__ int sbuf[CSR_CAP];
  __shared__ int wsum[4];
  int k = blockIdx.x, t = threadIdx.x, l = t & 63, w = t >> 6;
  cnt[t] = 0; cur[t] = 0;
  // inline top-level scan of btot
  {
    int bv = (t < nsb) ? btot[t] : 0;
    int vv = bv;
    #pragma unroll
    for (int o = 1; o < 64; o <<= 1) { int u = __shfl_up(vv, o); if (l >= o) vv += u; }
    if (l == 63) wsum[w] = vv;
    __syncthreads();
    int add = 0;
    #pragma unroll
    for (int j = 0; j < 4; ++j) if (j < w) add += wsum[j];
    sboff[t] = vv + add - bv;
  }
  __syncthreads();
  int r0 = sboff[k];
  int r1 = (k + 1 < nsb) ? sboff[k + 1] : E;
  int len = r1 - r0;
  bool fits = len <= CSR_CAP;
  if (fits) {
    for (int i = t; i < len; i += 256) {
      unsigned s = stage[r0 + i];
      ebuf[i] = s;
      atomicAdd(&cnt[s >> 17], 1);
    }
  } else {
    for (int i = r0 + t; i < r1; i += 256) atomicAdd(&cnt[stage[i] >> 17], 1);
  }
  __syncthreads();
  {  // 256-entry exclusive scan (4 waves)
    int v = cnt[t], orig = v;
    #pragma unroll
    for (int o = 1; o < 64; o <<= 1) {
      int u = __shfl_up(v, o);
      if (l >= o) v += u;
    }
    if (l == 63) wsum[w] = v;
    __syncthreads();
    int add = 0;
    #pragma unroll
    for (int j = 0; j < 4; ++j) if (j < w) add += wsum[j];
    int excl = v + add - orig;
    off[t] = excl;
    int n = (k << SSHIFT) + t;
    if (n < N) {
      row_ptr[n] = r0 + excl;
      dinv[n] = rsqrtf((float)(orig + 1));
    }
    if (k == nsb - 1 && t == 255) row_ptr[N] = E;
  }
  __syncthreads();
  if (fits) {
    for (int i = t; i < len; i += 256) {
      unsigned s = ebuf[i];
      int dl = s >> 17;
      int pos = off[dl] + atomicAdd(&cur[dl], 1);
      sbuf[pos] = (int)(s & 0x1FFFF);
    }
    __syncthreads();
    for (int i = t; i < len; i += 256) csr[r0 + i] = sbuf[i];
  } else {
    for (int i = r0 + t; i < r1; i += 256) {
      unsigned s = stage[i];
      int dl = s >> 17;
      int pos = r0 + off[dl] + atomicAdd(&cur[dl], 1);
      csr[pos] = (int)(s & 0x1FFFF);
    }
  }
}

// ---------- g(bf16, row-major) = dinv[n]*(x@W1), MFMA split-bf16 ----------
// x-tile split hi/lo ONCE per k-step into LDS (shared by all 4 waves).
__global__ __launch_bounds__(256) void gemm_k(const float* __restrict__ x,
    const float* __restrict__ W, const float* __restrict__ dinv,
    unsigned* __restrict__ gu, int nrows) {
  __shared__ unsigned short Bh[16384];   // W hi  [kstep][coltile][lane][j]
  __shared__ unsigned short Bl[16384];   // W lo
  __shared__ unsigned short Ah[4096];    // x hi  [kg][row][j]  (one k-step)
  __shared__ unsigned short Al[4096];    // x lo
  int t = threadIdx.x, l = t & 63, w = t >> 6;
  // stage W split hi/lo into fragment-ready layout (once)
  for (int idx = t; idx < 16384; idx += 256) {
    int k = idx >> 7, col = idx & 127;
    unsigned short hb, lb;
    split1(W[idx], hb, lb);
    int addr = (((k >> 5) * 8 + (col >> 4)) * 64 +
                (((k >> 3) & 3) * 16 + (col & 15))) * 8 + (k & 7);
    Bh[addr] = hb;
    Bl[addr] = lb;
  }

  int row0 = blockIdx.x * 128;
  int ct0 = w * 2;                       // wave's two col-tiles
  float4v acc[8][2];
  #pragma unroll
  for (int i = 0; i < 8; ++i) { acc[i][0] = (float4v)0.f; acc[i][1] = (float4v)0.f; }
  int arow = l & 15;
  int kg = l >> 4;
  int srow = t >> 1, skh = t & 1;        // staging: thread -> (row, k-half)
  int sgrow = min(row0 + srow, nrows - 1);

  for (int ks = 0; ks < 4; ++ks) {
    __syncthreads();                     // Ah/Al free (or W stage done)
    {                                    // split this k-step's x-tile
      const float* xp = &x[(size_t)sgrow * CIN + ks * 32 + skh * 16];
      float f[16];
      *(float4*)&f[0]  = *(const float4*)xp;
      *(float4*)&f[4]  = *(const float4*)(xp + 4);
      *(float4*)&f[8]  = *(const float4*)(xp + 8);
      *(float4*)&f[12] = *(const float4*)(xp + 12);
      #pragma unroll
      for (int h = 0; h < 2; ++h) {
        short8v ah_, al_;
        #pragma unroll
        for (int j = 0; j < 8; ++j) {
          unsigned short hb, lb;
          split1(f[h * 8 + j], hb, lb);
          ah_[j] = (short)hb;
          al_[j] = (short)lb;
        }
        int g = skh * 2 + h;
        *(short8v*)&Ah[(g * 128 + srow) * 8] = ah_;
        *(short8v*)&Al[(g * 128 + srow) * 8] = al_;
      }
    }
    __syncthreads();
    short8v bh0 = *(short8v*)&Bh[((ks * 8 + ct0) * 64 + l) * 8];
    short8v bh1 = *(short8v*)&Bh[((ks * 8 + ct0 + 1) * 64 + l) * 8];
    short8v bl0 = *(short8v*)&Bl[((ks * 8 + ct0) * 64 + l) * 8];
    short8v bl1 = *(short8v*)&Bl[((ks * 8 + ct0 + 1) * 64 + l) * 8];
    #pragma unroll
    for (int rt = 0; rt < 8; ++rt) {
      int ar = arow + rt * 16;
      short8v ah = *(short8v*)&Ah[(kg * 128 + ar) * 8];
      short8v al = *(short8v*)&Al[(kg * 128 + ar) * 8];
      acc[rt][0] = __builtin_amdgcn_mfma_f32_16x16x32_bf16(ah, bh0, acc[rt][0], 0, 0, 0);
      acc[rt][1] = __builtin_amdgcn_mfma_f32_16x16x32_bf16(ah, bh1, acc[rt][1], 0, 0, 0);
      acc[rt][0] = __builtin_amdgcn_mfma_f32_16x16x32_bf16(ah, bl0, acc[rt][0], 0, 0, 0);
      acc[rt][1] = __builtin_amdgcn_mfma_f32_16x16x32_bf16(ah, bl1, acc[rt][1], 0, 0, 0);
      acc[rt][0] = __builtin_amdgcn_mfma_f32_16x16x32_bf16(al, bh0, acc[rt][0], 0, 0, 0);
      acc[rt][1] = __builtin_amdgcn_mfma_f32_16x16x32_bf16(al, bh1, acc[rt][1], 0, 0, 0);
    }
  }
  // epilogue: D col = l&15, row = 4*(l>>4)+reg [HW-verified]; row-major gu
  #pragma unroll
  for (int rt = 0; rt < 8; ++rt) {
    #pragma unroll
    for (int r = 0; r < 4; ++r) {
      int row = row0 + rt * 16 + (l >> 4) * 4 + r;
      bool ok = row < nrows;
      float dv = ok ? dinv[row] : 0.f;
      #pragma unroll
      for (int c = 0; c < 2; ++c) {
        float val = acc[rt][c][r] * dv;
        float other = __shfl_xor(val, 1);
        int col = (ct0 + c) * 16 + (l & 15);
        if (ok && !(l & 1)) gu[(size_t)row * 64 + (col >> 1)] = pack_bf16x2(val, other);
      }
    }
  }
}

// ---------- propagate-1: 16-lane x uint4 row gather + fused epilogue ----------
#define ACC8(U) do { \
  acc[0] += bf_lo((U).x); acc[1] += bf_hi((U).x); \
  acc[2] += bf_lo((U).y); acc[3] += bf_hi((U).y); \
  acc[4] += bf_lo((U).z); acc[5] += bf_hi((U).z); \
  acc[6] += bf_lo((U).w); acc[7] += bf_hi((U).w); } while (0)

__global__ __launch_bounds__(256) void prop1_k(const uint4* __restrict__ g4,
    const int* __restrict__ row_ptr, const int* __restrict__ csr,
    const float* __restrict__ dinv, const float* __restrict__ b1,
    const float* __restrict__ Wout, unsigned* __restrict__ g2w,
    int n_nodes, int n_waves) {
  int l = threadIdx.x & 63;
  int q = l & 15, sub = l >> 4;     // lane q covers cols 8q..8q+7; sub owns j=2sub,2sub+1
  int wid = (blockIdx.x * blockDim.x + threadIdx.x) >> 6;
  float wj0[8], wj1[8], bb[8];
  #pragma unroll
  for (int c = 0; c < 8; ++c) {
    int col = 8 * q + c;
    wj0[c] = Wout[sub * 256 + col * 2];
    wj1[c] = Wout[sub * 256 + col * 2 + 1];
    bb[c] = b1[col];
  }
  for (int n = wid; n < n_nodes; n += n_waves) {
    int start = row_ptr[n], end = row_ptr[n + 1];
    float d = dinv[n];
    float acc[8];
    #pragma unroll
    for (int c = 0; c < 8; ++c) acc[c] = 0.f;
    for (int base = start; base < end; base += 64) {
      int cnt = min(64, end - base);
      int eb = (base + l < end) ? csr[base + l] : 0;
      int i = 0;
      for (; i + 16 <= cnt; i += 16) {
        int s0 = __shfl(eb, i + sub);
        int s1 = __shfl(eb, i + 4 + sub);
        int s2 = __shfl(eb, i + 8 + sub);
        int s3 = __shfl(eb, i + 12 + sub);
        uint4 u0 = g4[s0 * 16 + q];
        uint4 u1 = g4[s1 * 16 + q];
        uint4 u2 = g4[s2 * 16 + q];
        uint4 u3 = g4[s3 * 16 + q];
        ACC8(u0); ACC8(u1); ACC8(u2); ACC8(u3);
      }
      for (; i + 4 <= cnt; i += 4) {
        int s0 = __shfl(eb, i + sub);
        uint4 u0 = g4[s0 * 16 + q];
        ACC8(u0);
      }
      if (i < cnt) {
        int idx = i + sub;
        bool vld = idx < cnt;
        int s0 = __shfl(eb, vld ? idx : i);
        uint4 u0 = g4[s0 * 16 + q];
        if (vld) { ACC8(u0); }
      }
    }
    #pragma unroll
    for (int c = 0; c < 8; ++c) {   // merge the 4 sub-waves
      acc[c] += __shfl_xor(acc[c], 16);
      acc[c] += __shfl_xor(acc[c], 32);
    }
    uint4 us = g4[n * 16 + q];       // self-loop (dinv folded in g)
    ACC8(us);
    float p0 = 0.f, p1 = 0.f;
    #pragma unroll
    for (int c = 0; c < 8; ++c) {
      float y = fmaxf(fmaf(acc[c], d, bb[c]), 0.f);
      p0 = fmaf(y, wj0[c], p0);
      p1 = fmaf(y, wj1[c], p1);
    }
    #pragma unroll
    for (int off = 1; off < 16; off <<= 1) {
      p0 += __shfl_xor(p0, off);
      p1 += __shfl_xor(p1, off);
    }
    if (q == 0) g2w[n * 4 + sub] = pack_bf16x2(d * p0, d * p1);
  }
}

// ---------- propagate-2: 2 threads/node, uint2 bf16x4 per edge ----------
__global__ __launch_bounds__(256) void prop2_k(const uint2* __restrict__ g2v,
    const int* __restrict__ row_ptr, const int* __restrict__ csr,
    const float* __restrict__ dinv, const float* __restrict__ bout,
    float* __restrict__ out, int N) {
  int tid = blockIdx.x * 256 + threadIdx.x;
  int n = tid >> 1, hf = tid & 1;
  if (n >= N) return;
  uint2 us = g2v[n * 2 + hf];      // self-loop
  float a0 = bf_lo(us.x), a1 = bf_hi(us.x);
  float a2 = bf_lo(us.y), a3 = bf_hi(us.y);
  int e = row_ptr[n], e1 = row_ptr[n + 1];
  for (; e + 4 <= e1; e += 4) {
    int i0 = csr[e], i1 = csr[e + 1], i2 = csr[e + 2], i3 = csr[e + 3];
    uint2 u0 = g2v[i0 * 2 + hf], u1 = g2v[i1 * 2 + hf];
    uint2 u2 = g2v[i2 * 2 + hf], u3 = g2v[i3 * 2 + hf];
    a0 += (bf_lo(u0.x) + bf_lo(u1.x)) + (bf_lo(u2.x) + bf_lo(u3.x));
    a1 += (bf_hi(u0.x) + bf_hi(u1.x)) + (bf_hi(u2.x) + bf_hi(u3.x));
    a2 += (bf_lo(u0.y) + bf_lo(u1.y)) + (bf_lo(u2.y) + bf_lo(u3.y));
    a3 += (bf_hi(u0.y) + bf_hi(u1.y)) + (bf_hi(u2.y) + bf_hi(u3.y));
  }
  for (; e < e1; ++e) {
    uint2 u = g2v[csr[e] * 2 + hf];
    a0 += bf_lo(u.x); a1 += bf_hi(u.x);
    a2 += bf_lo(u.y); a3 += bf_hi(u.y);
  }
  float d = dinv[n];
  float2 o0 = make_float2(fmaf(d, a0, bout[hf * 4 + 0]), fmaf(d, a1, bout[hf * 4 + 1]));
  float2 o1 = make_float2(fmaf(d, a2, bout[hf * 4 + 2]), fmaf(d, a3, bout[hf * 4 + 3]));
  *(float2*)&out[(size_t)(hf * 2 + 0) * (2 * N) + 2 * n] = o0;
  *(float2*)&out[(size_t)(hf * 2 + 1) * (2 * N) + 2 * n] = o1;
}

extern "C" void kernel_launch(void* const* d_in, const int* in_sizes, int n_in,
                              void* d_out, int out_size, void* d_ws, size_t ws_size,
                              hipStream_t stream) {
  const float* x    = (const float*)d_in[0];
  const int*   ei   = (const int*)d_in[1];
  const float* W1   = (const float*)d_in[2];
  const float* b1   = (const float*)d_in[3];
  const float* Wout = (const float*)d_in[4];
  const float* bout = (const float*)d_in[5];
  float* out = (float*)d_out;

  const int N = in_sizes[0] / CIN;       // 50000
  const int E = in_sizes[1] / 2;         // 1600000
  const int* srcp = ei;
  const int* dstp = ei + E;
  const int NSB = (N + 255) >> SSHIFT;   // 196 super-buckets
  const int NSC = NSB * NBLKB;           // 50176 scan entries

  char* ws = (char*)d_ws;
  size_t off = 0;
  auto alloc = [&](size_t bytes) -> void* {
    void* p = ws + off;
    off = (off + bytes + 511) & ~(size_t)511;
    return p;
  };
  unsigned*       gu        = (unsigned*)alloc((size_t)N * 64 * 4);      // bf16 g, row-major
  unsigned short* g2u       = (unsigned short*)alloc((size_t)N * 8 * 2); // bf16 g2
  float*          dinv      = (float*)alloc((size_t)N * 4);
  int*            blockhist = (int*)alloc((size_t)NSC * 4);
  int*            soff      = (int*)alloc((size_t)NSC * 4);
  int*            btot      = (int*)alloc(256 * 4);
  int*            row_ptr   = (int*)alloc((size_t)(N + 1) * 4);
  int*            csr       = (int*)alloc((size_t)E * 4);
  unsigned*       stage     = (unsigned*)alloc((size_t)E * 4);
  (void)ws_size; (void)n_in; (void)out_size;

  histsb_k<<<NBLKB, 256, 0, stream>>>(dstp, blockhist, E, NSB);
  scan_k<<<NSB, 256, 0, stream>>>(blockhist, soff, btot, NSC);
  stageB_k<<<NBLKB, 256, 0, stream>>>(srcp, dstp, soff, btot, stage, E, NSB);
  csrsb_k<<<NSB, 256, 0, stream>>>(stage, btot, row_ptr, csr, dinv, N, E, NSB);

  gemm_k<<<(N + 127) / 128, 256, 0, stream>>>(x, W1, dinv, gu, N);

  const int P1_BLOCKS = 2048;
  prop1_k<<<P1_BLOCKS, 256, 0, stream>>>((const uint4*)gu, row_ptr, csr, dinv, b1,
                                         Wout, (unsigned*)g2u, N, P1_BLOCKS * 4);
  prop2_k<<<(2 * N + 255) / 256, 256, 0, stream>>>((const uint2*)g2u, row_ptr, csr,
                                                   dinv, bout, out, N);
}